// Round 11
// baseline (287.589 us; speedup 1.0000x reference)
//
#include <hip/hip_runtime.h>
#include <hip/hip_bf16.h>

#define PI_F 3.14159265358979323846f
#define NBLK 256     // chunk count for count/scatter passes (scan width)
#define BSH 8        // coarse bucket = 256 dst nodes
#define BSZ 256      // nodes per bucket
#define SCAP 10240   // LDS edge staging capacity (mean 8192, +22 sigma)
#define SLDS 3072    // agg1 per-block csr staging (64 nodes)
#define SLDS3 1536   // agg2/3 per-block csr staging (32 nodes, mean 1024, +16 sigma)

static inline size_t align256(size_t x) { return (x + 255) & ~size_t(255); }

typedef float v2f __attribute__((ext_vector_type(2)));
typedef unsigned uvec4 __attribute__((ext_vector_type(4)));   // native vector: NT-store legal

// bf16 helpers (bit tricks; round-to-nearest via +0x8000)
__device__ __forceinline__ unsigned bfpack(float a, float b) {
    unsigned lo = (__float_as_uint(a) + 0x8000u) >> 16;
    unsigned hi = (__float_as_uint(b) + 0x8000u) & 0xFFFF0000u;
    return lo | hi;
}

// unpack 4 fp8 (one dword) scaled by rs into a[0..3]
__device__ __forceinline__ void f8w(unsigned w, float rs, float* a) {
    v2f lo = __builtin_amdgcn_cvt_pk_f32_fp8(w, false);
    v2f hi = __builtin_amdgcn_cvt_pk_f32_fp8(w, true);
    a[0] += rs * lo.x; a[1] += rs * lo.y; a[2] += rs * hi.x; a[3] += rs * hi.y;
}

// accumulate one 16B fp8 half-row (16 features) scaled by rs into acc[16]
__device__ __forceinline__ void f8acc16(uint4 q, float rs, float acc[16]) {
    f8w(q.x, rs, acc); f8w(q.y, rs, acc + 4); f8w(q.z, rs, acc + 8); f8w(q.w, rs, acc + 12);
}

// ---------------- atomic-free bucketed CSR build ----------------

__global__ void __launch_bounds__(1024) count_kernel(
                             const int* __restrict__ dst, int* __restrict__ C,
                             int E, int CHUNK, int NB2) {
    extern __shared__ int hist[];   // NB2 ints
    for (int i = threadIdx.x; i < NB2; i += 1024) hist[i] = 0;
    __syncthreads();
    int s0 = blockIdx.x * CHUNK, s1 = min(s0 + CHUNK, E);
    for (int e = s0 + threadIdx.x; e < s1; e += 1024)
        atomicAdd(&hist[dst[e] >> BSH], 1);
    __syncthreads();
    for (int i = threadIdx.x; i < NB2; i += 1024)
        C[(size_t)blockIdx.x * NB2 + i] = hist[i];
}

__global__ void scan_blocks_kernel(int* __restrict__ C, int* __restrict__ colsum, int NB2) {
    __shared__ int s[256];
    int k = blockIdx.x;
    int b = threadIdx.x;
    int v = C[(size_t)b * NB2 + k];
    s[b] = v;
    __syncthreads();
    for (int off = 1; off < 256; off <<= 1) {
        int w = (b >= off) ? s[b - off] : 0;
        __syncthreads();
        s[b] += w;
        __syncthreads();
    }
    C[(size_t)b * NB2 + k] = s[b] - v;   // exclusive
    if (b == 255) colsum[k] = s[255];
}

__global__ void scan_totals_kernel(const int* __restrict__ colsum, int* __restrict__ bbase,
                                   int NB2, int E) {
    __shared__ int s[256];
    __shared__ int running;
    if (threadIdx.x == 0) running = 0;
    __syncthreads();
    for (int base = 0; base < NB2; base += 256) {
        int i = base + threadIdx.x;
        int v = (i < NB2) ? colsum[i] : 0;
        s[threadIdx.x] = v;
        __syncthreads();
        for (int off = 1; off < 256; off <<= 1) {
            int w = (threadIdx.x >= (unsigned)off) ? s[threadIdx.x - off] : 0;
            __syncthreads();
            s[threadIdx.x] += w;
            __syncthreads();
        }
        if (i < NB2) bbase[i] = running + s[threadIdx.x] - v;
        __syncthreads();
        if (threadIdx.x == 255) running += s[255];
        __syncthreads();
    }
    if (threadIdx.x == 0) bbase[NB2] = E;
}

__global__ void __launch_bounds__(1024) scatter_kernel(
                               const int* __restrict__ src, const int* __restrict__ dst,
                               const int* __restrict__ C, const int* __restrict__ bbase,
                               unsigned* __restrict__ bkt_data, int E, int CHUNK, int NB2) {
    extern __shared__ int ofs[];   // NB2 ints
    for (int i = threadIdx.x; i < NB2; i += 1024)
        ofs[i] = bbase[i] + C[(size_t)blockIdx.x * NB2 + i];
    __syncthreads();
    int s0 = blockIdx.x * CHUNK, s1 = min(s0 + CHUNK, E);
    for (int e = s0 + threadIdx.x; e < s1; e += 1024) {
        int d = dst[e];
        int p = atomicAdd(&ofs[d >> BSH], 1);   // LDS atomic only
        bkt_data[p] = ((unsigned)(d & (BSZ - 1)) << 17) | (unsigned)src[e];
    }
}

__global__ void __launch_bounds__(512) csr_build_kernel(
                                 const unsigned* __restrict__ bkt_data, const int* __restrict__ bbase,
                                 const float* __restrict__ x,
                                 unsigned* __restrict__ csr, int* __restrict__ e_start,
                                 float* __restrict__ dinv, float* __restrict__ xd,
                                 int N, int NB2) {
    __shared__ unsigned sdata[SCAP];
    __shared__ int hist[256];
    __shared__ int scn[256];
    __shared__ int bump[256];
    int tid = threadIdx.x;
    int b = blockIdx.x;
    int g0 = bbase[b], g1 = bbase[b + 1];
    int cnt = g1 - g0;
    bool fits = (cnt <= SCAP);
    if (tid < 256) hist[tid] = 0;
    __syncthreads();
    for (int i = tid; i < cnt; i += 512) {
        unsigned pk = bkt_data[g0 + i];
        if (fits) sdata[i] = pk;
        atomicAdd(&hist[pk >> 17], 1);
    }
    __syncthreads();
    int orig = (tid < 256) ? hist[tid] : 0;
    if (tid < 256) scn[tid] = orig;
    __syncthreads();
    for (int off = 1; off < 256; off <<= 1) {
        int w = (tid >= off && tid < 256) ? scn[tid - off] : 0;
        __syncthreads();
        if (tid < 256) scn[tid] += w;
        __syncthreads();
    }
    if (tid < 256) {
        int excl = scn[tid] - orig;
        bump[tid] = g0 + excl;
        int node = b * BSZ + tid;
        if (node < N) {
            float dv = rsqrtf((float)(orig + 1));
            dinv[node] = dv;
            xd[node] = x[node] * dv;
            e_start[node] = g0 + excl;
        }
    }
    if (b == NB2 - 1 && tid == 0) e_start[N] = g1;
    __syncthreads();
    for (int i = tid; i < cnt; i += 512) {
        unsigned pk = fits ? sdata[i] : bkt_data[g0 + i];
        int p = atomicAdd(&bump[pk >> 17], 1);
        csr[p] = pk & 0x1FFFFu;
    }
}

// ---------------- GCN layers ----------------
// Intermediate rows: fp8 e4m3 [32] (32B) + f32 per-row scale -> 3.6 MB, L2-resident.

// stage contiguous csr slice into LDS (NT load); 256-thread sweep.
__device__ __forceinline__ bool stage_csr(const unsigned* __restrict__ csr,
                                          const int* __restrict__ e_start,
                                          int d0, int dEnd, int* sidx, int cap, int& E0) {
    E0 = e_start[d0];
    int E1 = e_start[dEnd];
    int m = E1 - E0;
    bool fits = (m <= cap);
    if (fits) {
        for (int i = threadIdx.x; i < m; i += 256)
            sidx[i] = (int)__builtin_nontemporal_load(&csr[E0 + i]);
    }
    __syncthreads();
    return fits;
}

// ---- agg1: 4 lanes/node (unchanged from round 10) ----
__device__ __forceinline__ void mm32_8(const float* __restrict__ sW, const float vr[8],
                                       int sub, int lane, float o[8]) {
    const float4* sW4 = (const float4*)sW;
    int base = lane & ~3;
#pragma unroll
    for (int r = 0; r < 4; r++) {
#pragma unroll
        for (int i = 0; i < 8; i++) {
            float vk = __shfl(vr[i], base | r, 64);
            int k = r * 8 + i;
            float4 w0 = sW4[k * 8 + sub * 2];
            float4 w1 = sW4[k * 8 + sub * 2 + 1];
            o[0] += vk * w0.x; o[1] += vk * w0.y; o[2] += vk * w0.z; o[3] += vk * w0.w;
            o[4] += vk * w1.x; o[5] += vk * w1.y; o[6] += vk * w1.z; o[7] += vk * w1.w;
        }
    }
}

__device__ __forceinline__ void store_f8_q(unsigned char* __restrict__ u8, float* __restrict__ uscale,
                                           int d, int sub, const float o[8]) {
    float am = 0.f;
#pragma unroll
    for (int i = 0; i < 8; i++) am = fmaxf(am, fabsf(o[i]));
    am = fmaxf(am, __shfl_xor(am, 1, 64));
    am = fmaxf(am, __shfl_xor(am, 2, 64));
    float rm = fmaxf(am, 1e-20f);
    float sc = 128.f / rm;
    unsigned w0 = 0, w1 = 0;
    w0 = __builtin_amdgcn_cvt_pk_fp8_f32(o[0] * sc, o[1] * sc, w0, false);
    w0 = __builtin_amdgcn_cvt_pk_fp8_f32(o[2] * sc, o[3] * sc, w0, true);
    w1 = __builtin_amdgcn_cvt_pk_fp8_f32(o[4] * sc, o[5] * sc, w1, false);
    w1 = __builtin_amdgcn_cvt_pk_fp8_f32(o[6] * sc, o[7] * sc, w1, true);
    uint2 st; st.x = w0; st.y = w1;
    ((uint2*)u8)[(size_t)d * 4 + sub] = st;
    if (sub == 0) uscale[d] = rm * (1.f / 128.f);
}

__global__ void __launch_bounds__(256) agg1_kernel(
                            const float* __restrict__ xd, const int* __restrict__ e_start,
                            const unsigned* __restrict__ csr, const float* __restrict__ dinv,
                            const float* __restrict__ W1, const float* __restrict__ b1,
                            const float* __restrict__ W2,
                            unsigned char* __restrict__ u8o, float* __restrict__ uso, int n) {
    __shared__ float sW2[1024];
    __shared__ float sW1[32], sb1[32];
    __shared__ int sidx[SLDS];
    for (int i = threadIdx.x; i < 1024; i += 256) sW2[i] = W2[i];
    if (threadIdx.x < 32) { sW1[threadIdx.x] = W1[threadIdx.x]; sb1[threadIdx.x] = b1[threadIdx.x]; }
    int d0 = blockIdx.x * 64;
    int dEnd = min(d0 + 64, n);
    int E0;
    bool fits = stage_csr(csr, e_start, d0, dEnd, sidx, SLDS, E0);
    int d = d0 + (threadIdx.x >> 2), sub = threadIdx.x & 3;
    int lane = threadIdx.x & 63;
    if (d >= n) return;
    int e0 = e_start[d];
    int cnt = e_start[d + 1] - e0;
    int l0 = e0 - E0;
    float s = 0.f;
    int j = sub;
    if (fits) {
        for (; j < cnt; j += 4) s += xd[sidx[l0 + j]];
    } else {
        for (; j < cnt; j += 4) s += xd[(int)csr[e0 + j]];
    }
    s += __shfl_xor(s, 1, 64);
    s += __shfl_xor(s, 2, 64);
    float dv = dinv[d];
    float tt = dv * (s + xd[d]);
    float vr[8];
#pragma unroll
    for (int i = 0; i < 8; i++) vr[i] = fmaxf(tt * sW1[sub * 8 + i] + sb1[sub * 8 + i], 0.f);
    float o[8];
#pragma unroll
    for (int i = 0; i < 8; i++) o[i] = 0.f;
    mm32_8(sW2, vr, sub, lane, o);
#pragma unroll
    for (int i = 0; i < 8; i++) o[i] *= dv;
    store_f8_q(u8o, uso, d, sub, o);
}

// ---- agg2/agg3: 8 lanes/node = 4 edge-slots x 2 half-rows ----
// lane bits: 0 = half, 1-2 = slot, 3-5 = node-in-wave. Per load instruction a wave
// covers 8 nodes x 4 edges = 32 distinct rows in flight (64 with unroll-2).

// gather: acc[16] = sum over this slot's edges of rs * fp8 half-row; then slot-reduce.
__device__ __forceinline__ void gather_f8h(const unsigned char* __restrict__ u8,
                                           const float* __restrict__ uscale,
                                           const int* __restrict__ sidx, bool fits,
                                           const unsigned* __restrict__ csr,
                                           int e0, int l0, int cnt, int d,
                                           int half, int slot, float acc[16]) {
#pragma unroll
    for (int i = 0; i < 16; i++) acc[i] = 0.f;
    const uint4* rows = (const uint4*)u8;
    int j = slot;
    if (fits) {
        for (; j + 4 < cnt; j += 8) {
            int ia = sidx[l0 + j];
            int ib = sidx[l0 + j + 4];
            float ra = uscale[ia], rb = uscale[ib];
            uint4 qa = rows[(size_t)ia * 2 + half];
            uint4 qb = rows[(size_t)ib * 2 + half];
            f8acc16(qa, ra, acc);
            f8acc16(qb, rb, acc);
        }
        if (j < cnt) {
            int ia = sidx[l0 + j];
            f8acc16(rows[(size_t)ia * 2 + half], uscale[ia], acc);
        }
    } else {
        for (; j + 4 < cnt; j += 8) {
            int ia = (int)csr[e0 + j];
            int ib = (int)csr[e0 + j + 4];
            float ra = uscale[ia], rb = uscale[ib];
            uint4 qa = rows[(size_t)ia * 2 + half];
            uint4 qb = rows[(size_t)ib * 2 + half];
            f8acc16(qa, ra, acc);
            f8acc16(qb, rb, acc);
        }
        if (j < cnt) {
            int ia = (int)csr[e0 + j];
            f8acc16(rows[(size_t)ia * 2 + half], uscale[ia], acc);
        }
    }
    if (slot == 0) {   // self row once
        f8acc16(rows[(size_t)d * 2 + half], uscale[d], acc);
    }
    // reduce over 4 slots (lane bits 1,2); afterwards every lane holds the full sum
#pragma unroll
    for (int i = 0; i < 16; i++) {
        acc[i] += __shfl_xor(acc[i], 2, 64);
        acc[i] += __shfl_xor(acc[i], 4, 64);
    }
}

// o[0..15] = full 32-k matvec for this half: o[i] = sum_k v[k]*W[k][half*16+i].
__device__ __forceinline__ void mm32_16(const float* __restrict__ sW, const float vr[16],
                                        int half, int lane, float o[16]) {
    const float4* sW4 = (const float4*)sW;
    int nb = lane & ~7;
#pragma unroll
    for (int k = 0; k < 32; k++) {
        float vk = __shfl(vr[k & 15], nb | (k >> 4), 64);
        float4 w0 = sW4[k * 8 + half * 4 + 0];
        float4 w1 = sW4[k * 8 + half * 4 + 1];
        float4 w2 = sW4[k * 8 + half * 4 + 2];
        float4 w3 = sW4[k * 8 + half * 4 + 3];
        o[0]  += vk * w0.x; o[1]  += vk * w0.y; o[2]  += vk * w0.z; o[3]  += vk * w0.w;
        o[4]  += vk * w1.x; o[5]  += vk * w1.y; o[6]  += vk * w1.z; o[7]  += vk * w1.w;
        o[8]  += vk * w2.x; o[9]  += vk * w2.y; o[10] += vk * w2.z; o[11] += vk * w2.w;
        o[12] += vk * w3.x; o[13] += vk * w3.y; o[14] += vk * w3.z; o[15] += vk * w3.w;
    }
}

// agg2: gather; v=relu(dv*acc+b); out = fp8(dv*(v@W)) + per-row scale.
__global__ void __launch_bounds__(256) agg2_kernel(
                            const unsigned char* __restrict__ u8, const float* __restrict__ uscale,
                            const int* __restrict__ e_start, const unsigned* __restrict__ csr,
                            const float* __restrict__ dinv, const float* __restrict__ bias,
                            const float* __restrict__ W,
                            unsigned char* __restrict__ o8, float* __restrict__ oscale, int n) {
    __shared__ float sW[1024];
    __shared__ float sb[32];
    __shared__ int sidx[SLDS3];
    for (int i = threadIdx.x; i < 1024; i += 256) sW[i] = W[i];
    if (threadIdx.x < 32) sb[threadIdx.x] = bias[threadIdx.x];
    int d0 = blockIdx.x * 32;
    int dEnd = min(d0 + 32, n);
    int E0;
    bool fits = stage_csr(csr, e_start, d0, dEnd, sidx, SLDS3, E0);
    int d = d0 + (threadIdx.x >> 3);
    int half = threadIdx.x & 1, slot = (threadIdx.x >> 1) & 3;
    int lane = threadIdx.x & 63;
    if (d >= n) return;
    int e0 = e_start[d];
    int cnt = e_start[d + 1] - e0;
    float acc[16];
    gather_f8h(u8, uscale, sidx, fits, csr, e0, e0 - E0, cnt, d, half, slot, acc);
    float dv = dinv[d];
    float vr[16];
#pragma unroll
    for (int i = 0; i < 16; i++) vr[i] = fmaxf(dv * acc[i] + sb[half * 16 + i], 0.f);
    float o[16];
#pragma unroll
    for (int i = 0; i < 16; i++) o[i] = 0.f;
    mm32_16(sW, vr, half, lane, o);
#pragma unroll
    for (int i = 0; i < 16; i++) o[i] *= dv;
    float am = 0.f;
#pragma unroll
    for (int i = 0; i < 16; i++) am = fmaxf(am, fabsf(o[i]));
    am = fmaxf(am, __shfl_xor(am, 1, 64));   // across halves (slots identical)
    float rm = fmaxf(am, 1e-20f);
    float sc = 128.f / rm;
    unsigned w[4];
#pragma unroll
    for (int p = 0; p < 4; p++) {
        unsigned t = 0;
        t = __builtin_amdgcn_cvt_pk_fp8_f32(o[4 * p + 0] * sc, o[4 * p + 1] * sc, t, false);
        t = __builtin_amdgcn_cvt_pk_fp8_f32(o[4 * p + 2] * sc, o[4 * p + 3] * sc, t, true);
        w[p] = t;
    }
    if (slot == 0) {
        uint4 st; st.x = w[0]; st.y = w[1]; st.z = w[2]; st.w = w[3];
        ((uint4*)o8)[(size_t)d * 2 + half] = st;
        if (half == 0) oscale[d] = rm * (1.f / 128.f);
    }
}

// agg3: v=relu(dv*acc+b3) -> hb (bf16, NT); theta = PI*sigmoid(relu(v@Wt1+bt1)@Wt2+bt2).
__global__ void __launch_bounds__(256) agg3_kernel(
                            const unsigned char* __restrict__ u8, const float* __restrict__ uscale,
                            const int* __restrict__ e_start, const unsigned* __restrict__ csr,
                            const float* __restrict__ dinv, const float* __restrict__ bias,
                            const float* __restrict__ Wt1, const float* __restrict__ bt1,
                            const float* __restrict__ Wt2, const float* __restrict__ bt2,
                            unsigned short* __restrict__ hb, float* __restrict__ theta, int n) {
    __shared__ float sW[1024];
    __shared__ float sb[32], sbt[32], sw2[32];
    __shared__ int sidx[SLDS3];
    for (int i = threadIdx.x; i < 1024; i += 256) sW[i] = Wt1[i];
    if (threadIdx.x < 32) {
        sb[threadIdx.x] = bias[threadIdx.x];
        sbt[threadIdx.x] = bt1[threadIdx.x];
        sw2[threadIdx.x] = Wt2[threadIdx.x];
    }
    int d0 = blockIdx.x * 32;
    int dEnd = min(d0 + 32, n);
    int E0;
    bool fits = stage_csr(csr, e_start, d0, dEnd, sidx, SLDS3, E0);
    int d = d0 + (threadIdx.x >> 3);
    int half = threadIdx.x & 1, slot = (threadIdx.x >> 1) & 3;
    int lane = threadIdx.x & 63;
    if (d >= n) return;
    int e0 = e_start[d];
    int cnt = e_start[d + 1] - e0;
    float acc[16];
    gather_f8h(u8, uscale, sidx, fits, csr, e0, e0 - E0, cnt, d, half, slot, acc);
    float dv = dinv[d];
    float vr[16];
#pragma unroll
    for (int i = 0; i < 16; i++) vr[i] = fmaxf(dv * acc[i] + sb[half * 16 + i], 0.f);
    if (slot == 0) {
        uvec4 s0, s1;
        s0.x = bfpack(vr[0], vr[1]);   s0.y = bfpack(vr[2], vr[3]);
        s0.z = bfpack(vr[4], vr[5]);   s0.w = bfpack(vr[6], vr[7]);
        s1.x = bfpack(vr[8], vr[9]);   s1.y = bfpack(vr[10], vr[11]);
        s1.z = bfpack(vr[12], vr[13]); s1.w = bfpack(vr[14], vr[15]);
        __builtin_nontemporal_store(s0, (uvec4*)hb + (size_t)d * 4 + half * 2);
        __builtin_nontemporal_store(s1, (uvec4*)hb + (size_t)d * 4 + half * 2 + 1);
    }
    float o[16];
#pragma unroll
    for (int i = 0; i < 16; i++) o[i] = 0.f;
    mm32_16(sW, vr, half, lane, o);
    float tl = 0.f;
#pragma unroll
    for (int i = 0; i < 16; i++)
        tl += fmaxf(o[i] + sbt[half * 16 + i], 0.f) * sw2[half * 16 + i];
    tl += __shfl_xor(tl, 1, 64);   // halves (slots identical)
    if (half == 0 && slot == 0)
        __builtin_nontemporal_store(PI_F / (1.f + __expf(-(tl + bt2[0]))), theta + d);
}

// ---------------- pooled head: boundary index + block-per-graph reduce ----------------

__global__ void gb_kernel(const int* __restrict__ batch, int* __restrict__ gstart,
                          int n, int G) {
    int i = blockIdx.x * 256 + threadIdx.x;
    if (i >= n) return;
    int g = batch[i];
    if (i == 0) {
        for (int gg = 0; gg <= g; gg++) gstart[gg] = 0;
    } else {
        int gp = batch[i - 1];
        for (int gg = gp + 1; gg <= g; gg++) gstart[gg] = i;
    }
    if (i == n - 1) {
        for (int gg = g + 1; gg <= G; gg++) gstart[gg] = n;
    }
}

__global__ void __launch_bounds__(512) bg_kernel(
                          const unsigned short* __restrict__ hb, const int* __restrict__ gstart,
                          const float* __restrict__ Wg1, const float* __restrict__ bg1v,
                          const float* __restrict__ Wg2, const float* __restrict__ bg2v,
                          float* __restrict__ out, int G) {
    __shared__ float sW[1024];
    __shared__ float part[8][32];
    for (int i = threadIdx.x; i < 1024; i += 512) sW[i] = Wg1[i];
    int g = blockIdx.x;
    int s = gstart[g], e = gstart[g + 1];
    int w = threadIdx.x >> 6;
    int lane = threadIdx.x & 63;
    int f = lane & 31, h = lane >> 5;
    float a = 0.f;
    for (int i = s + (w << 1) + h; i < e; i += 16)
        a += __uint_as_float((unsigned)hb[((size_t)i << 5) + f] << 16);
    a += __shfl_xor(a, 32, 64);
    if (h == 0) part[w][f] = a;
    __syncthreads();
    if (w == 0) {
        float hv = 0.f;
#pragma unroll
        for (int p = 0; p < 8; p++) hv += part[p][f];
        hv /= fmaxf((float)(e - s), 1.f);
        int base = lane & 32;
        float acc = bg1v[f];
#pragma unroll
        for (int k = 0; k < 32; k++) acc += __shfl(hv, base | k, 64) * sW[k * 32 + f];
        acc = fmaxf(acc, 0.f);
        float p0 = acc * Wg2[f * 2 + 0];
        float p1 = acc * Wg2[f * 2 + 1];
#pragma unroll
        for (int m = 1; m < 32; m <<= 1) {
            p0 += __shfl_xor(p0, m, 64);
            p1 += __shfl_xor(p1, m, 64);
        }
        if (f == 0) {
            out[g * 2 + 0] = 2.f * PI_F / (1.f + __expf(-(p0 + bg2v[0])));
            out[g * 2 + 1] = 2.f * PI_F / (1.f + __expf(-(p1 + bg2v[1])));
        }
    }
}

// ---------------- launch ----------------

extern "C" void kernel_launch(void* const* d_in, const int* in_sizes, int n_in,
                              void* d_out, int out_size, void* d_ws, size_t ws_size,
                              hipStream_t stream) {
    const float* x   = (const float*)d_in[0];
    const int*   ei  = (const int*)d_in[1];
    const int* batch = (const int*)d_in[2];
    const float* W1  = (const float*)d_in[3];
    const float* b1  = (const float*)d_in[4];
    const float* W2  = (const float*)d_in[5];
    const float* b2  = (const float*)d_in[6];
    const float* W3  = (const float*)d_in[7];
    const float* b3  = (const float*)d_in[8];
    const float* Wt1 = (const float*)d_in[9];
    const float* bt1 = (const float*)d_in[10];
    const float* Wt2 = (const float*)d_in[11];
    const float* bt2 = (const float*)d_in[12];
    const float* Wg1 = (const float*)d_in[13];
    const float* bg1 = (const float*)d_in[14];
    const float* Wg2 = (const float*)d_in[15];
    const float* bg2 = (const float*)d_in[16];

    const int N = in_sizes[0];
    const int E = in_sizes[1] / 2;
    const int G = 128;
    const int* src = ei;
    const int* dst = ei + E;
    float* theta_out = (float*)d_out;
    float* bg_out = (float*)d_out + N;

    const int NB2 = (N + BSZ - 1) >> BSH;
    const int CHUNK = (E + NBLK - 1) / NBLK;

    char* w = (char*)d_ws;
    auto alloc = [&](size_t bytes) -> char* { char* p = w; w += align256(bytes); return p; };
    int*      C        = (int*)alloc((size_t)NBLK * NB2 * 4);
    int*      colsum   = (int*)alloc((size_t)NB2 * 4);
    int*      bbase    = (int*)alloc((size_t)(NB2 + 1) * 4);
    unsigned* bkt_data = (unsigned*)alloc((size_t)E * 4);
    unsigned* csr      = (unsigned*)alloc((size_t)E * 4);
    int*      e_start  = (int*)alloc((size_t)(N + 1) * 4);
    float*    dinv     = (float*)alloc((size_t)N * 4);
    float*    xd       = (float*)alloc((size_t)N * 4);
    unsigned char* u2  = (unsigned char*)alloc((size_t)N * 32);
    float*    us2      = (float*)alloc((size_t)N * 4);
    unsigned char* u3  = (unsigned char*)alloc((size_t)N * 32);
    float*    us3      = (float*)alloc((size_t)N * 4);
    unsigned short* hb = (unsigned short*)alloc((size_t)N * 64);
    int*      gstart   = (int*)alloc((size_t)(G + 1) * 4);

    size_t ldsB = (size_t)NB2 * 4;
    count_kernel<<<NBLK, 1024, ldsB, stream>>>(dst, C, E, CHUNK, NB2);
    scan_blocks_kernel<<<NB2, 256, 0, stream>>>(C, colsum, NB2);
    scan_totals_kernel<<<1, 256, 0, stream>>>(colsum, bbase, NB2, E);
    scatter_kernel<<<NBLK, 1024, ldsB, stream>>>(src, dst, C, bbase, bkt_data, E, CHUNK, NB2);
    csr_build_kernel<<<NB2, 512, 0, stream>>>(bkt_data, bbase, x, csr, e_start, dinv, xd, N, NB2);
    gb_kernel<<<(N + 255) / 256, 256, 0, stream>>>(batch, gstart, N, G);

    unsigned gridQ = (unsigned)(((size_t)N * 4 + 255) / 256);   // agg1: 4 threads/node
    unsigned gridH = (unsigned)(((size_t)N * 8 + 255) / 256);   // agg2/3: 8 threads/node

    agg1_kernel<<<gridQ, 256, 0, stream>>>(xd, e_start, csr, dinv, W1, b1, W2, u2, us2, N);
    agg2_kernel<<<gridH, 256, 0, stream>>>(u2, us2, e_start, csr, dinv, b2, W3, u3, us3, N);
    agg3_kernel<<<gridH, 256, 0, stream>>>(u3, us3, e_start, csr, dinv, b3,
                                           Wt1, bt1, Wt2, bt2, hb, theta_out, N);

    bg_kernel<<<G, 512, 0, stream>>>(hb, gstart, Wg1, bg1, Wg2, bg2, bg_out, G);
}